// Round 7
// baseline (207.034 us; speedup 1.0000x reference)
//
#include <hip/hip_runtime.h>
#include <cstdint>

#define T_LEN 4096
#define S_DIM 308
#define S_PAD 320
#define E_DIM 126
#define NBATCH 32
#define NCHUNK 128
#define CHL 32
#define WARM 6      // contraction ~0.066/step -> ~1e-6 relative after warm-up
#define FSTR 132    // inF row stride in f32 (128+4: spreads banks for frag reads)

typedef _Float16 half8 __attribute__((ext_vector_type(8)));
typedef float floatx4 __attribute__((ext_vector_type(4)));

union HU8 { uint4 u; half8 h; };
union HU1 { uint16_t u; _Float16 h; };

__device__ __forceinline__ half8 h8_from_u4(uint4 v) { HU8 t; t.u = v; return t.h; }

// ---- merged init: blocks 0..49 pack A-frags, 50..69 pack B-frags, 70 zeroes out ----
// A-frag (MFMA B-operand for P=Q@A): tile = nt*10 + kt (nt<20, kt<10);
//   lane l holds A[k=kt*32+(l>>4)*8+j][n=nt*16+(l&15)], j=0..7 -> one uint4.
// B-frag (MFMA B-operand for E=inp@Bt): tile = nt*4 + kt over E padded to 128,
//   value = 128*B[n][k] (the x128 pre-scale telescopes into the loglik).
__global__ __launch_bounds__(256) void init_pack(const float* __restrict__ A,
                                                 const float* __restrict__ Bm,
                                                 uint32_t* __restrict__ Apk,
                                                 uint32_t* __restrict__ Bfr,
                                                 float* __restrict__ out) {
  int blk = blockIdx.x, tid = threadIdx.x;
  if (blk < 50) {
    int idx = blk * 256 + tid;                 // 200 tiles * 64 lanes
    int lane = idx & 63, tile = idx >> 6;
    int kt = tile % 10, nt = tile / 10;
    int n  = nt * 16 + (lane & 15);
    int k0 = kt * 32 + (lane >> 4) * 8;
    uint32_t wv[4];
#pragma unroll
    for (int jj = 0; jj < 4; jj++) {
      int ka = k0 + 2 * jj, kb = ka + 1;
      float x0 = (n < S_DIM && ka < S_DIM) ? A[ka * S_DIM + n] : 0.f;
      float x1 = (n < S_DIM && kb < S_DIM) ? A[kb * S_DIM + n] : 0.f;
      HU1 h0, h1; h0.h = (_Float16)x0; h1.h = (_Float16)x1;
      wv[jj] = (uint32_t)h0.u | ((uint32_t)h1.u << 16);
    }
    uint4 o; o.x = wv[0]; o.y = wv[1]; o.z = wv[2]; o.w = wv[3];
    ((uint4*)Apk)[idx] = o;
  } else if (blk < 70) {
    int idx = (blk - 50) * 256 + tid;          // 80 tiles * 64 lanes
    int lane = idx & 63, tile = idx >> 6;
    int kt = tile % 4, nt = tile / 4;
    int n  = nt * 16 + (lane & 15);
    int k0 = kt * 32 + (lane >> 4) * 8;
    uint32_t wv[4];
#pragma unroll
    for (int jj = 0; jj < 4; jj++) {
      int ka = k0 + 2 * jj, kb = ka + 1;
      float x0 = (n < S_DIM && ka < E_DIM) ? 128.f * Bm[n * E_DIM + ka] : 0.f;
      float x1 = (n < S_DIM && kb < E_DIM) ? 128.f * Bm[n * E_DIM + kb] : 0.f;
      HU1 h0, h1; h0.h = (_Float16)x0; h1.h = (_Float16)x1;
      wv[jj] = (uint32_t)h0.u | ((uint32_t)h1.u << 16);
    }
    uint4 o; o.x = wv[0]; o.y = wv[1]; o.z = wv[2]; o.w = wv[3];
    ((uint4*)Bfr)[idx] = o;
  } else {
    if (tid < NBATCH) out[tid] = 0.f;
  }
}

// ---- fully fused recursion: emission GEMM + alpha MFMA in one kernel ----
// Block = (chunk c, 16 batches). 640 thr = 10 waves, 2 n-tiles each.
// Per step i (t = t_first-1+i):
//   a) E = inp_t @ Bt'  (8 MFMA from LDS-staged f32 rows, B-frags in regs)
//      Q = Pacc ⊙ E     (pure register f32 mul — E and P share C-layout!)
//      [checkpoints: z = Σ_n Q -> register shuffle + LDS atomics]
//   b) write Q to LDS in A-operand granule layout; commit prefetched inp rows
//   c) barrier; d) Pacc = Q @ A (20 MFMA, A-frags in regs); issue next prefetch
//   e) barrier. P stays f32 in registers the whole chunk (better precision
//      than the old f16 LDS round-trip). loglik telescopes between 2 z-checkpoints.
__global__ __launch_bounds__(640, 2)
void hmm_fused(const uint32_t* __restrict__ Apk,
               const uint32_t* __restrict__ Bfr,
               const float* __restrict__ inp,
               const float* __restrict__ Ivec,
               float* __restrict__ out) {
  __shared__ float inF[2][16 * FSTR];
  __shared__ __attribute__((aligned(16))) uint4 Qf[640];
  __shared__ float zslot[16];
  int c = blockIdx.x, bbase = blockIdx.y * 16;
  int tid = threadIdx.x, lane = tid & 63, w = tid >> 6;
  int gl = lane & 15, quad = lane >> 4;

  half8 bfA[2][10], bfB[2][4];
#pragma unroll
  for (int q = 0; q < 2; q++) {
#pragma unroll
    for (int kt = 0; kt < 10; kt++)
      bfA[q][kt] = h8_from_u4(((const uint4*)Apk)[((w * 2 + q) * 10 + kt) * 64 + lane]);
#pragma unroll
    for (int kt = 0; kt < 4; kt++)
      bfB[q][kt] = h8_from_u4(((const uint4*)Bfr)[((w * 2 + q) * 4 + kt) * 64 + lane]);
  }
#pragma unroll
  for (int q = 0; q < 2; q++) {
#pragma unroll
    for (int kt = 0; kt < 10; kt++) asm volatile("" : "+v"(bfA[q][kt]));
#pragma unroll
    for (int kt = 0; kt < 4; kt++)  asm volatile("" : "+v"(bfB[q][kt]));
  }

  // Pacc init in C-layout: P0[*][n] = Ivec[n] (c==0) or 1; pad n -> 0.
  float Pa[2][4];
#pragma unroll
  for (int q = 0; q < 2; q++) {
    int n = (w * 2 + q) * 16 + gl;
    float v = (n < S_DIM) ? (c == 0 ? Ivec[n] : 1.0f) : 0.f;
#pragma unroll
    for (int r = 0; r < 4; r++) Pa[q][r] = v;
  }
  if (tid < 16) zslot[tid] = 0.f;

  int t_first = (c == 0) ? 1 : c * CHL - WARM + 1;
  int nstep   = (c == 0) ? (CHL - 1) : (CHL + WARM - 1);   // 31 or 37
  int iw      = (c == 0) ? -1 : (WARM - 1);                // z at t = c*CHL-1
  int t_last  = t_first - 1 + nstep;

  // stage rows for t0 = t_first-1 directly; prefetch t_first into registers
  {
    int t0 = t_first - 1;
#pragma unroll
    for (int s = 0; s < 4; s++) {
      int flat = tid + s * 640;
      if (flat < 2048) {
        int r = flat >> 7, col = flat & 127;
        inF[0][r * FSTR + col] =
            (col < E_DIM) ? inp[((size_t)(bbase + r) * T_LEN + t0) * E_DIM + col] : 0.f;
      }
    }
  }
  float g[4];
#pragma unroll
  for (int s = 0; s < 4; s++) {
    int flat = tid + s * 640;
    g[s] = 0.f;
    if (flat < 2048) {
      int r = flat >> 7, col = flat & 127;
      int tp = (t_first <= t_last) ? t_first : t_last;
      if (col < E_DIM) g[s] = inp[((size_t)(bbase + r) * T_LEN + tp) * E_DIM + col];
    }
  }
  float llw = 0.f;
  __syncthreads();

  _Float16* Qh = (_Float16*)Qf;

  for (int i = 0; i <= nstep; i++) {
    int cur = i & 1, nxt = cur ^ 1;
    // ---- a) E-MFMA from inF[cur]
    half8 af_e[4];
#pragma unroll
    for (int kt = 0; kt < 4; kt++) {
      const float* fp = &inF[cur][gl * FSTR + kt * 32 + quad * 8];
      float4 v0 = *(const float4*)fp;
      float4 v1 = *(const float4*)(fp + 4);
      half8 h;
      h[0] = (_Float16)v0.x; h[1] = (_Float16)v0.y; h[2] = (_Float16)v0.z; h[3] = (_Float16)v0.w;
      h[4] = (_Float16)v1.x; h[5] = (_Float16)v1.y; h[6] = (_Float16)v1.z; h[7] = (_Float16)v1.w;
      af_e[kt] = h;
    }
    floatx4 Ea[2];
    Ea[0] = (floatx4){0.f, 0.f, 0.f, 0.f};
    Ea[1] = (floatx4){0.f, 0.f, 0.f, 0.f};
#pragma unroll
    for (int kt = 0; kt < 4; kt++) {
      Ea[0] = __builtin_amdgcn_mfma_f32_16x16x32_f16(af_e[kt], bfB[0][kt], Ea[0], 0, 0, 0);
      Ea[1] = __builtin_amdgcn_mfma_f32_16x16x32_f16(af_e[kt], bfB[1][kt], Ea[1], 0, 0, 0);
    }
    // Q = P ⊙ E (registers, same C-layout)
    float qv[2][4];
#pragma unroll
    for (int q = 0; q < 2; q++)
#pragma unroll
      for (int r = 0; r < 4; r++) qv[q][r] = Pa[q][r] * Ea[q][r];
    // checkpoints: z[m] = Σ_n Q[m][n]
    if (i == iw || i == nstep) {
      float s0 = qv[0][0] + qv[1][0], s1 = qv[0][1] + qv[1][1];
      float s2 = qv[0][2] + qv[1][2], s3 = qv[0][3] + qv[1][3];
#pragma unroll
      for (int off = 1; off <= 8; off <<= 1) {
        s0 += __shfl_xor(s0, off); s1 += __shfl_xor(s1, off);
        s2 += __shfl_xor(s2, off); s3 += __shfl_xor(s3, off);
      }
      if (gl == 0) {
        atomicAdd(&zslot[quad * 4 + 0], s0);
        atomicAdd(&zslot[quad * 4 + 1], s1);
        atomicAdd(&zslot[quad * 4 + 2], s2);
        atomicAdd(&zslot[quad * 4 + 3], s3);
      }
    }
    // ---- b) write Q (f16) into A-operand granule layout; commit prefetched rows
#pragma unroll
    for (int q = 0; q < 2; q++) {
      int k = (w * 2 + q) * 16 + gl;
      int off_base = ((k >> 5) * 64 + 16 * ((k >> 3) & 3)) * 8 + (k & 7);
#pragma unroll
      for (int r = 0; r < 4; r++)
        Qh[off_base + (quad * 4 + r) * 8] = (_Float16)qv[q][r];
    }
    if (i < nstep) {
#pragma unroll
      for (int s = 0; s < 4; s++) {
        int flat = tid + s * 640;
        if (flat < 2048) inF[nxt][(flat >> 7) * FSTR + (flat & 127)] = g[s];
      }
    }
    __syncthreads();
    // ---- post-barrier: checkpoint finalize / exit
    if (i == iw && tid < 16) { llw = logf(zslot[tid]); zslot[tid] = 0.f; }
    if (i == nstep) {
      if (tid < 16) {
        float lle = logf(zslot[tid]);
        // CHL accounted steps between checkpoints, each carrying one x128
        atomicAdd(&out[bbase + tid], lle - llw - 32.0f * 4.852030263919617f);
      }
      break;
    }
    // ---- d) P = Q @ A ; issue prefetch for t+2
    floatx4 acc0 = (floatx4){0.f, 0.f, 0.f, 0.f};
    floatx4 acc1 = (floatx4){0.f, 0.f, 0.f, 0.f};
#pragma unroll
    for (int kt = 0; kt < 10; kt++) {
      half8 afv = h8_from_u4(Qf[kt * 64 + lane]);
      acc0 = __builtin_amdgcn_mfma_f32_16x16x32_f16(afv, bfA[0][kt], acc0, 0, 0, 0);
      acc1 = __builtin_amdgcn_mfma_f32_16x16x32_f16(afv, bfA[1][kt], acc1, 0, 0, 0);
    }
#pragma unroll
    for (int r = 0; r < 4; r++) { Pa[0][r] = acc0[r]; Pa[1][r] = acc1[r]; }
    {
      int tp = t_first - 1 + i + 2; if (tp > t_last) tp = t_last;
#pragma unroll
      for (int s = 0; s < 4; s++) {
        int flat = tid + s * 640;
        g[s] = 0.f;
        if (flat < 2048) {
          int r = flat >> 7, col = flat & 127;
          if (col < E_DIM) g[s] = inp[((size_t)(bbase + r) * T_LEN + tp) * E_DIM + col];
        }
      }
    }
    __syncthreads();   // Qf reads done before next overwrite; inF[cur] free
  }
}

extern "C" void kernel_launch(void* const* d_in, const int* in_sizes, int n_in,
                              void* d_out, int out_size, void* d_ws, size_t ws_size,
                              hipStream_t stream) {
  const float* inp = (const float*)d_in[0];   // [32,4096,126]
  const float* A   = (const float*)d_in[1];   // [308,308]
  const float* Bm  = (const float*)d_in[2];   // [308,126]
  const float* Iv  = (const float*)d_in[3];   // [308]
  float* out = (float*)d_out;                 // [32]

  uint8_t* ws = (uint8_t*)d_ws;
  uint32_t* Apk = (uint32_t*)(ws);                 // 200 KiB
  uint32_t* Bfr = (uint32_t*)(ws + (256u << 10));  // 80 KiB

  hipLaunchKernelGGL(init_pack, dim3(71), dim3(256), 0, stream, A, Bm, Apk, Bfr, out);
  hipLaunchKernelGGL(hmm_fused, dim3(NCHUNK, NBATCH / 16), dim3(640), 0, stream,
                     Apk, Bfr, inp, Iv, out);
}

// Round 8
// 170.783 us; speedup vs baseline: 1.2123x; 1.2123x over previous
//
#include <hip/hip_runtime.h>
#include <cstdint>

#define T_LEN 4096
#define S_DIM 308
#define S_PAD 320
#define E_DIM 126
#define NBATCH 32
#define NCHUNK 128
#define CHL 32
#define WARM 6      // contraction ~0.066/step -> ~1e-6 relative after warm-up
#define SSTR 88     // emis_stream LDS strip row stride in f16

typedef _Float16 half8 __attribute__((ext_vector_type(8)));
typedef float floatx4 __attribute__((ext_vector_type(4)));

union HU8 { uint4 u; half8 h; };
union HU1 { uint16_t u; _Float16 h; };

__device__ __forceinline__ half8 h8_from_u4(uint4 v) { HU8 t; t.u = v; return t.h; }
__device__ __forceinline__ uint4 u4_from_h8(half8 v) { HU8 t; t.h = v; return t.u; }

// ---- merged init: blocks 0..49 pack A-frags, 50..69 pack B-frags, 70 zeroes out ----
// A-frag (MFMA B-op for P=Q@A): tile = nt*10 + kt; lane l holds
//   A[k=kt*32+(l>>4)*8+j][n=nt*16+(l&15)], j=0..7 -> one uint4.
// B-frag (MFMA B-op for E=inp@Bt): tile = nt*4 + kt over E padded to 128,
//   value = 128*B[n][k] (x128 pre-scale telescopes into the loglik).
__global__ __launch_bounds__(256) void init_pack(const float* __restrict__ A,
                                                 const float* __restrict__ Bm,
                                                 uint32_t* __restrict__ Apk,
                                                 uint32_t* __restrict__ Bfr,
                                                 float* __restrict__ out) {
  int blk = blockIdx.x, tid = threadIdx.x;
  if (blk < 50) {
    int idx = blk * 256 + tid;                 // 200 tiles * 64 lanes
    int lane = idx & 63, tile = idx >> 6;
    int kt = tile % 10, nt = tile / 10;
    int n  = nt * 16 + (lane & 15);
    int k0 = kt * 32 + (lane >> 4) * 8;
    uint32_t wv[4];
#pragma unroll
    for (int jj = 0; jj < 4; jj++) {
      int ka = k0 + 2 * jj, kb = ka + 1;
      float x0 = (n < S_DIM && ka < S_DIM) ? A[ka * S_DIM + n] : 0.f;
      float x1 = (n < S_DIM && kb < S_DIM) ? A[kb * S_DIM + n] : 0.f;
      HU1 h0, h1; h0.h = (_Float16)x0; h1.h = (_Float16)x1;
      wv[jj] = (uint32_t)h0.u | ((uint32_t)h1.u << 16);
    }
    uint4 o; o.x = wv[0]; o.y = wv[1]; o.z = wv[2]; o.w = wv[3];
    ((uint4*)Apk)[idx] = o;
  } else if (blk < 70) {
    int idx = (blk - 50) * 256 + tid;          // 80 tiles * 64 lanes
    int lane = idx & 63, tile = idx >> 6;
    int kt = tile % 4, nt = tile / 4;
    int n  = nt * 16 + (lane & 15);
    int k0 = kt * 32 + (lane >> 4) * 8;
    uint32_t wv[4];
#pragma unroll
    for (int jj = 0; jj < 4; jj++) {
      int ka = k0 + 2 * jj, kb = ka + 1;
      float x0 = (n < S_DIM && ka < E_DIM) ? 128.f * Bm[n * E_DIM + ka] : 0.f;
      float x1 = (n < S_DIM && kb < E_DIM) ? 128.f * Bm[n * E_DIM + kb] : 0.f;
      HU1 h0, h1; h0.h = (_Float16)x0; h1.h = (_Float16)x1;
      wv[jj] = (uint32_t)h0.u | ((uint32_t)h1.u << 16);
    }
    uint4 o; o.x = wv[0]; o.y = wv[1]; o.z = wv[2]; o.w = wv[3];
    ((uint4*)Bfr)[idx] = o;
  } else {
    if (tid < NBATCH) out[tid] = 0.f;
  }
}

// ---- emission GEMM, barrier-free per-wave streaming ----
// emis2[t][b][s] = 128 * sum_e inp[b,t,e]*B[s,e], f16.
// Each wave owns a 16-row (b,t)-tile end-to-end: direct global A-frag loads
// (masked float2, 64B-line coalesced), 20 MFMA over its 5 n-tiles, output
// coalesced via a wave-PRIVATE LDS strip (no __syncthreads in the kernel).
// Depth-2 register prefetch across the 4 tiles each wave processes.
__global__ __launch_bounds__(256) void emis_stream(const float* __restrict__ inp,
                                                   const uint32_t* __restrict__ Bfr,
                                                   uint16_t* __restrict__ emis2) {
  __shared__ __attribute__((aligned(16))) _Float16 strip[4][16 * SSTR];
  int tid = threadIdx.x, lane = tid & 63, w = tid >> 6;
  int gl = lane & 15, quad = lane >> 4;
  half8 bf[5][4];
#pragma unroll
  for (int q = 0; q < 5; q++)
#pragma unroll
    for (int kt = 0; kt < 4; kt++)
      bf[q][kt] = h8_from_u4(((const uint4*)Bfr)[((w * 5 + q) * 4 + kt) * 64 + lane]);

  int tbase = blockIdx.x * 4;                  // 2048 blocks * 4 tiles
  float2 g[16];
  // issue tile loads: row = tile*16+gl, cols kt*32+quad*8+sub*2
#define ISSUE(tileIdx, dst)                                                     \
  {                                                                             \
    const float* rp = inp + (size_t)((tileIdx) * 16 + gl) * E_DIM;              \
    _Pragma("unroll")                                                           \
    for (int jj = 0; jj < 16; jj++) {                                           \
      int k = (jj >> 2) * 32 + quad * 8 + (jj & 3) * 2;                         \
      if (k < E_DIM) dst[jj] = *(const float2*)(rp + k);                        \
      else { dst[jj].x = 0.f; dst[jj].y = 0.f; }                                \
    }                                                                           \
  }
  ISSUE(tbase, g);
  for (int j = 0; j < 4; j++) {
    float2 h[16];
    if (j < 3) ISSUE(tbase + j + 1, h);
    // build A-frags from g
    half8 af[4];
#pragma unroll
    for (int kt = 0; kt < 4; kt++) {
      half8 x;
#pragma unroll
      for (int sub = 0; sub < 4; sub++) {
        x[2 * sub]     = (_Float16)g[kt * 4 + sub].x;
        x[2 * sub + 1] = (_Float16)g[kt * 4 + sub].y;
      }
      af[kt] = x;
    }
    floatx4 acc[5];
#pragma unroll
    for (int q = 0; q < 5; q++) acc[q] = (floatx4){0.f, 0.f, 0.f, 0.f};
#pragma unroll
    for (int kt = 0; kt < 4; kt++)
#pragma unroll
      for (int q = 0; q < 5; q++)
        acc[q] = __builtin_amdgcn_mfma_f32_16x16x32_f16(af[kt], bf[q][kt], acc[q], 0, 0, 0);
    // stage to wave-private strip (C-layout -> row-major); wave-coherent, no barrier
#pragma unroll
    for (int q = 0; q < 5; q++)
#pragma unroll
      for (int r = 0; r < 4; r++)
        strip[w][(quad * 4 + r) * SSTR + q * 16 + gl] = (_Float16)acc[q][r];
    // coalesced store: 16 rows x 80 f16 -> emis2[(t0+r)*32+b][w*80..]
    int tIdx = tbase + j;
    int b = (tIdx * 16) >> 12, t0 = (tIdx * 16) & 4095;
#pragma unroll
    for (int s = 0; s < 3; s++) {
      int flat = lane + s * 64;
      if (flat < 160) {
        int r = flat / 10, d = flat % 10;
        uint4 v = *(const uint4*)&strip[w][r * SSTR + d * 8];
        *(uint4*)&emis2[((size_t)(t0 + r) * NBATCH + b) * S_PAD + w * 80 + d * 8] = v;
      }
    }
#pragma unroll
    for (int jj = 0; jj < 16; jj++) g[jj] = h[jj];
  }
#undef ISSUE
}

// ---- MFMA alpha recursion (R6 structure), e' from [t][b][s] layout ----
// Thread tid <-> Q granule tid: row=tid&15, qd=(tid>>4)&3, kt=tid>>6 (== w).
// phase-a: Q[tid] = P[row][kt*32+qd*8..+7] ⊙ e'; phase-b: P = Q @ A (MFMA,
// A-frags register-resident). Loglik telescopes via Q-sums at 2 checkpoints.
__global__ __launch_bounds__(640, 2)
void hmm_forward(const uint32_t* __restrict__ Apk,
                 const uint16_t* __restrict__ emis2,
                 const float* __restrict__ Ivec,
                 float* __restrict__ out) {
  __shared__ __attribute__((aligned(16))) _Float16 Pm[16 * 328];
  __shared__ __attribute__((aligned(16))) uint4 Qf[640];
  __shared__ float zslot[16];
  int c = blockIdx.x, bbase = blockIdx.y * 16;
  int tid = threadIdx.x, lane = tid & 63, w = tid >> 6;

  half8 bfrag[2][10];
#pragma unroll
  for (int q = 0; q < 2; q++)
#pragma unroll
    for (int kt = 0; kt < 10; kt++)
      bfrag[q][kt] = h8_from_u4(((const uint4*)Apk)[((w * 2 + q) * 10 + kt) * 64 + lane]);
#pragma unroll
  for (int q = 0; q < 2; q++)
#pragma unroll
    for (int kt = 0; kt < 10; kt++)
      asm volatile("" : "+v"(bfrag[q][kt]));

  int row = tid & 15, qd = (tid >> 4) & 3;    // kt for phase-a == w
  int colbase = w * 32 + qd * 8;
  int gl = lane & 15, quad = lane >> 4;

  {
    _Float16 pv[8];
#pragma unroll
    for (int jj = 0; jj < 8; jj++) {
      int mm = colbase + jj;
      pv[jj] = (_Float16)((mm < S_DIM) ? (c == 0 ? Ivec[mm] : 1.0f) : 0.f);
    }
    *(uint4*)&Pm[row * 328 + colbase] = *(const uint4*)pv;
  }
  if (tid < 16) zslot[tid] = 0.f;

  int t_first = (c == 0) ? 1 : c * CHL - WARM + 1;
  int nstep   = (c == 0) ? (CHL - 1) : (CHL + WARM - 1);   // 31 or 37
  int iw_r    = (c == 0) ? -1 : (WARM - 1);                // z at t = c*CHL-1
  // e' address in [t][b][s] layout: ((t*32 + b)*320 + colbase)
  size_t ecol = (size_t)(bbase + row) * S_PAD + colbase;
  uint4 epre = *(const uint4*)&emis2[(size_t)(t_first - 1) * NBATCH * S_PAD + ecol];
  float llw = 0.f;
  __syncthreads();

  for (int i = 0; i <= nstep; i++) {
    // ---- phase a: Q = P ⊙ e'
    half8 qv = h8_from_u4(*(const uint4*)&Pm[row * 328 + colbase]) * h8_from_u4(epre);
    Qf[tid] = u4_from_h8(qv);
    if (i < nstep)
      epre = *(const uint4*)&emis2[(size_t)(t_first + i) * NBATCH * S_PAD + ecol];
    if (i == iw_r || i == nstep) {
      float s = 0.f;
#pragma unroll
      for (int jj = 0; jj < 8; jj++) s += (float)qv[jj];
      atomicAdd(&zslot[row], s);
    }
    __syncthreads();
    if (i == iw_r && tid < 16) { llw = logf(zslot[tid]); zslot[tid] = 0.f; }
    if (i == nstep) {
      if (tid < 16) {
        float lle = logf(zslot[tid]);
        atomicAdd(&out[bbase + tid], lle - llw - 32.0f * 4.852030263919617f);
      }
      break;
    }
    // ---- phase b: P = Q @ A
    floatx4 acc0 = (floatx4){0.f, 0.f, 0.f, 0.f};
    floatx4 acc1 = (floatx4){0.f, 0.f, 0.f, 0.f};
#pragma unroll
    for (int kt = 0; kt < 10; kt++) {
      half8 afv = h8_from_u4(Qf[kt * 64 + lane]);
      acc0 = __builtin_amdgcn_mfma_f32_16x16x32_f16(afv, bfrag[0][kt], acc0, 0, 0, 0);
      acc1 = __builtin_amdgcn_mfma_f32_16x16x32_f16(afv, bfrag[1][kt], acc1, 0, 0, 0);
    }
#pragma unroll
    for (int r = 0; r < 4; r++) {
      Pm[(quad * 4 + r) * 328 + (w * 2 + 0) * 16 + gl] = (_Float16)acc0[r];
      Pm[(quad * 4 + r) * 328 + (w * 2 + 1) * 16 + gl] = (_Float16)acc1[r];
    }
    __syncthreads();
  }
}

extern "C" void kernel_launch(void* const* d_in, const int* in_sizes, int n_in,
                              void* d_out, int out_size, void* d_ws, size_t ws_size,
                              hipStream_t stream) {
  const float* inp = (const float*)d_in[0];   // [32,4096,126]
  const float* A   = (const float*)d_in[1];   // [308,308]
  const float* Bm  = (const float*)d_in[2];   // [308,126]
  const float* Iv  = (const float*)d_in[3];   // [308]
  float* out = (float*)d_out;                 // [32]

  uint8_t* ws = (uint8_t*)d_ws;
  uint32_t* Apk   = (uint32_t*)(ws);                 // 200 KiB
  uint32_t* Bfr   = (uint32_t*)(ws + (256u << 10));  // 80 KiB
  uint16_t* emis2 = (uint16_t*)(ws + (512u << 10));  // [4096][32][320] f16 = 83,886,080 B

  hipLaunchKernelGGL(init_pack,   dim3(71),   dim3(256), 0, stream, A, Bm, Apk, Bfr, out);
  hipLaunchKernelGGL(emis_stream, dim3(2048), dim3(256), 0, stream, inp, Bfr, emis2);
  hipLaunchKernelGGL(hmm_forward, dim3(NCHUNK, NBATCH / 16), dim3(640), 0, stream,
                     Apk, emis2, Iv, out);
}

// Round 9
// 156.872 us; speedup vs baseline: 1.3198x; 1.0887x over previous
//
#include <hip/hip_runtime.h>
#include <cstdint>

#define T_LEN 4096
#define S_DIM 308
#define S_PAD 320
#define E_DIM 126
#define NBATCH 32
#define NCHUNK 128
#define CHL 32
#define WARM 6     // contraction ~0.066/step -> ~1e-6 relative after warm-up
#define FH 136     // inH row stride (f16): 272B/row = 68 dw = 4 (mod 32) -> uniform banks
#define QSTR 336   // QL row stride (f16): 672B/row = 168 dw = 8 (mod 32) -> uniform b128

typedef _Float16 half8 __attribute__((ext_vector_type(8)));
typedef float floatx4 __attribute__((ext_vector_type(4)));

union HU8 { uint4 u; half8 h; };
union HU1 { uint16_t u; _Float16 h; };

__device__ __forceinline__ half8 h8_from_u4(uint4 v) { HU8 t; t.u = v; return t.h; }

// ---- merged init: blocks 0..49 pack A-frags, 50..69 pack B-frags, 70 zeroes out ----
// A-frag (MFMA B-op for P=Q@A): tile = nt*10 + kt; lane l holds
//   A[k=kt*32+(l>>4)*8+j][n=nt*16+(l&15)], j=0..7 -> one uint4.
// B-frag (MFMA B-op for E=inp@Bt): tile = nt*4 + kt over E padded to 128,
//   value = 128*B[n][k] (x128 pre-scale telescopes into the loglik).
__global__ __launch_bounds__(256) void init_pack(const float* __restrict__ A,
                                                 const float* __restrict__ Bm,
                                                 uint32_t* __restrict__ Apk,
                                                 uint32_t* __restrict__ Bfr,
                                                 float* __restrict__ out) {
  int blk = blockIdx.x, tid = threadIdx.x;
  if (blk < 50) {
    int idx = blk * 256 + tid;                 // 200 tiles * 64 lanes
    int lane = idx & 63, tile = idx >> 6;
    int kt = tile % 10, nt = tile / 10;
    int n  = nt * 16 + (lane & 15);
    int k0 = kt * 32 + (lane >> 4) * 8;
    uint32_t wv[4];
#pragma unroll
    for (int jj = 0; jj < 4; jj++) {
      int ka = k0 + 2 * jj, kb = ka + 1;
      float x0 = (n < S_DIM && ka < S_DIM) ? A[ka * S_DIM + n] : 0.f;
      float x1 = (n < S_DIM && kb < S_DIM) ? A[kb * S_DIM + n] : 0.f;
      HU1 h0, h1; h0.h = (_Float16)x0; h1.h = (_Float16)x1;
      wv[jj] = (uint32_t)h0.u | ((uint32_t)h1.u << 16);
    }
    uint4 o; o.x = wv[0]; o.y = wv[1]; o.z = wv[2]; o.w = wv[3];
    ((uint4*)Apk)[idx] = o;
  } else if (blk < 70) {
    int idx = (blk - 50) * 256 + tid;          // 80 tiles * 64 lanes
    int lane = idx & 63, tile = idx >> 6;
    int kt = tile % 4, nt = tile / 4;
    int n  = nt * 16 + (lane & 15);
    int k0 = kt * 32 + (lane >> 4) * 8;
    uint32_t wv[4];
#pragma unroll
    for (int jj = 0; jj < 4; jj++) {
      int ka = k0 + 2 * jj, kb = ka + 1;
      float x0 = (n < S_DIM && ka < E_DIM) ? 128.f * Bm[n * E_DIM + ka] : 0.f;
      float x1 = (n < S_DIM && kb < E_DIM) ? 128.f * Bm[n * E_DIM + kb] : 0.f;
      HU1 h0, h1; h0.h = (_Float16)x0; h1.h = (_Float16)x1;
      wv[jj] = (uint32_t)h0.u | ((uint32_t)h1.u << 16);
    }
    uint4 o; o.x = wv[0]; o.y = wv[1]; o.z = wv[2]; o.w = wv[3];
    ((uint4*)Bfr)[idx] = o;
  } else {
    if (tid < NBATCH) out[tid] = 0.f;
  }
}

// ---- fully fused recursion, round-2 (R7 fixed): ----
// Block (chunk c, 16 batches), 640 thr = 10 waves x 2 n-tiles.
// Per step: a) E-MFMA from f16-staged inp rows (8 MFMA; bfB in regs);
//              Q = P (.) E  -- pure register mul (shared C-layout);
//              write Q -> QL[i&1] granule (u16, stride-336: uniform banks);
//              commit prefetched inp rows -> inH[nxt] (f16, stride-136);
//           b) ONE barrier; P = Q @ A (20 MFMA; bfA in regs); issue t+2 loads.
// No Pm array, no second barrier (QL double-buffered), no e' intermediate
// in HBM at all. loglik telescopes between 2 checkpoint z-sums.
__global__ __launch_bounds__(640, 3)
void hmm_fused(const uint32_t* __restrict__ Apk,
               const uint32_t* __restrict__ Bfr,
               const float* __restrict__ inp,
               const float* __restrict__ Ivec,
               float* __restrict__ out) {
  __shared__ __attribute__((aligned(16))) _Float16 inH[2][16 * FH];
  __shared__ __attribute__((aligned(16))) _Float16 QL[2][16 * QSTR];
  __shared__ float zslot[16];
  int c = blockIdx.x, bbase = blockIdx.y * 16;
  int tid = threadIdx.x, lane = tid & 63, w = tid >> 6;
  int gl = lane & 15, quad = lane >> 4;

  half8 bfA[2][10], bfB[2][4];
#pragma unroll
  for (int q = 0; q < 2; q++) {
#pragma unroll
    for (int kt = 0; kt < 10; kt++)
      bfA[q][kt] = h8_from_u4(((const uint4*)Apk)[((w * 2 + q) * 10 + kt) * 64 + lane]);
#pragma unroll
    for (int kt = 0; kt < 4; kt++)
      bfB[q][kt] = h8_from_u4(((const uint4*)Bfr)[((w * 2 + q) * 4 + kt) * 64 + lane]);
  }
#pragma unroll
  for (int q = 0; q < 2; q++) {
#pragma unroll
    for (int kt = 0; kt < 10; kt++) asm volatile("" : "+v"(bfA[q][kt]));
#pragma unroll
    for (int kt = 0; kt < 4; kt++)  asm volatile("" : "+v"(bfB[q][kt]));
  }

  // P init in C-layout (rows m = batch streams)
  float Pa[2][4];
#pragma unroll
  for (int q = 0; q < 2; q++) {
    int n = (w * 2 + q) * 16 + gl;
    float v = (n < S_DIM) ? (c == 0 ? Ivec[n] : 1.0f) : 0.f;
#pragma unroll
    for (int r = 0; r < 4; r++) Pa[q][r] = v;
  }
  if (tid < 16) zslot[tid] = 0.f;

  int t_first = (c == 0) ? 1 : (c * CHL - WARM + 1);
  int nstep   = (c == 0) ? (CHL - 1) : (CHL + WARM - 1);   // 31 or 37
  int iw      = (c == 0) ? -1 : (WARM - 1);                // z at t = c*CHL-1
  int t_last  = t_first - 1 + nstep;

  // stage inH[0] <- rows at t0 = t_first-1 (cvt to f16); 1024 u32 slots:
  // r = flat>>6, c2 = flat&63; c2==63 zero-fills cols 126/127.
  {
    int t0 = t_first - 1;
#pragma unroll
    for (int s = 0; s < 2; s++) {
      int flat = tid + s * 640;
      if (flat < 1024) {
        int r = flat >> 6, c2 = flat & 63;
        float2 v; v.x = 0.f; v.y = 0.f;
        if (c2 < 63) v = *(const float2*)(inp + ((size_t)(bbase + r) * T_LEN + t0) * E_DIM + 2 * c2);
        HU1 a, b; a.h = (_Float16)v.x; b.h = (_Float16)v.y;
        *(uint32_t*)&inH[0][r * FH + 2 * c2] = (uint32_t)a.u | ((uint32_t)b.u << 16);
      }
    }
  }
  // prefetch rows at t_first into registers
  float2 g[2];
#pragma unroll
  for (int s = 0; s < 2; s++) {
    int flat = tid + s * 640;
    g[s].x = 0.f; g[s].y = 0.f;
    if (flat < 1024) {
      int r = flat >> 6, c2 = flat & 63;
      if (c2 < 63) g[s] = *(const float2*)(inp + ((size_t)(bbase + r) * T_LEN + t_first) * E_DIM + 2 * c2);
    }
  }
  float llw = 0.f;
  __syncthreads();

  for (int i = 0; i <= nstep; i++) {
    int cur = i & 1, nxt = cur ^ 1;
    // ---- phase a: E-MFMA from inH[cur]
    floatx4 Ea0 = (floatx4){0.f, 0.f, 0.f, 0.f};
    floatx4 Ea1 = (floatx4){0.f, 0.f, 0.f, 0.f};
#pragma unroll
    for (int kt = 0; kt < 4; kt++) {
      half8 af = h8_from_u4(*(const uint4*)&inH[cur][gl * FH + kt * 32 + quad * 8]);
      Ea0 = __builtin_amdgcn_mfma_f32_16x16x32_f16(af, bfB[0][kt], Ea0, 0, 0, 0);
      Ea1 = __builtin_amdgcn_mfma_f32_16x16x32_f16(af, bfB[1][kt], Ea1, 0, 0, 0);
    }
    // Q = P (.) E  (registers; identical C-layout)
    float qv[2][4];
#pragma unroll
    for (int r = 0; r < 4; r++) { qv[0][r] = Pa[0][r] * Ea0[r]; qv[1][r] = Pa[1][r] * Ea1[r]; }
    // checkpoints: z[m] = sum_n Q[m][n]
    if (i == iw || i == nstep) {
      float s0 = qv[0][0] + qv[1][0], s1 = qv[0][1] + qv[1][1];
      float s2 = qv[0][2] + qv[1][2], s3 = qv[0][3] + qv[1][3];
#pragma unroll
      for (int off = 1; off <= 8; off <<= 1) {
        s0 += __shfl_xor(s0, off); s1 += __shfl_xor(s1, off);
        s2 += __shfl_xor(s2, off); s3 += __shfl_xor(s3, off);
      }
      if (gl == 0) {
        atomicAdd(&zslot[quad * 4 + 0], s0);
        atomicAdd(&zslot[quad * 4 + 1], s1);
        atomicAdd(&zslot[quad * 4 + 2], s2);
        atomicAdd(&zslot[quad * 4 + 3], s3);
      }
    }
    // write Q -> granule [m][k] (A-operand layout for phase b)
#pragma unroll
    for (int q = 0; q < 2; q++) {
      int k = (w * 2 + q) * 16 + gl;
#pragma unroll
      for (int r = 0; r < 4; r++)
        QL[cur][(quad * 4 + r) * QSTR + k] = (_Float16)qv[q][r];
    }
    // commit prefetched rows (t_first+i) -> inH[nxt]
    if (i < nstep) {
#pragma unroll
      for (int s = 0; s < 2; s++) {
        int flat = tid + s * 640;
        if (flat < 1024) {
          int r = flat >> 6, c2 = flat & 63;
          HU1 a, b; a.h = (_Float16)g[s].x; b.h = (_Float16)g[s].y;
          uint32_t pv = (c2 < 63) ? ((uint32_t)a.u | ((uint32_t)b.u << 16)) : 0u;
          *(uint32_t*)&inH[nxt][r * FH + 2 * c2] = pv;
        }
      }
    }
    __syncthreads();   // the ONLY barrier per step
    if (i == iw && tid < 16) { llw = logf(zslot[tid]); zslot[tid] = 0.f; }
    if (i == nstep) {
      if (tid < 16) {
        float lle = logf(zslot[tid]);
        // CHL accounted steps between checkpoints, each carrying one x128
        atomicAdd(&out[bbase + tid], lle - llw - 32.0f * 4.852030263919617f);
      }
      break;
    }
    // ---- phase b: issue loads for t_first+i+1 (committed next step); P = Q @ A
    {
      int tp = t_first + i + 1; if (tp > t_last) tp = t_last;
#pragma unroll
      for (int s = 0; s < 2; s++) {
        int flat = tid + s * 640;
        g[s].x = 0.f; g[s].y = 0.f;
        if (flat < 1024) {
          int r = flat >> 6, c2 = flat & 63;
          if (c2 < 63) g[s] = *(const float2*)(inp + ((size_t)(bbase + r) * T_LEN + tp) * E_DIM + 2 * c2);
        }
      }
    }
    floatx4 acc0 = (floatx4){0.f, 0.f, 0.f, 0.f};
    floatx4 acc1 = (floatx4){0.f, 0.f, 0.f, 0.f};
#pragma unroll
    for (int kt = 0; kt < 10; kt++) {
      half8 afv = h8_from_u4(*(const uint4*)&QL[cur][gl * QSTR + kt * 32 + quad * 8]);
      acc0 = __builtin_amdgcn_mfma_f32_16x16x32_f16(afv, bfA[0][kt], acc0, 0, 0, 0);
      acc1 = __builtin_amdgcn_mfma_f32_16x16x32_f16(afv, bfA[1][kt], acc1, 0, 0, 0);
    }
#pragma unroll
    for (int r = 0; r < 4; r++) { Pa[0][r] = acc0[r]; Pa[1][r] = acc1[r]; }
    // no second barrier: QL is double-buffered, inH[cur] reads all pre-barrier
  }
}

extern "C" void kernel_launch(void* const* d_in, const int* in_sizes, int n_in,
                              void* d_out, int out_size, void* d_ws, size_t ws_size,
                              hipStream_t stream) {
  const float* inp = (const float*)d_in[0];   // [32,4096,126]
  const float* A   = (const float*)d_in[1];   // [308,308]
  const float* Bm  = (const float*)d_in[2];   // [308,126]
  const float* Iv  = (const float*)d_in[3];   // [308]
  float* out = (float*)d_out;                 // [32]

  uint8_t* ws = (uint8_t*)d_ws;
  uint32_t* Apk = (uint32_t*)(ws);                 // 200 KiB
  uint32_t* Bfr = (uint32_t*)(ws + (256u << 10));  // 80 KiB

  hipLaunchKernelGGL(init_pack, dim3(71), dim3(256), 0, stream, A, Bm, Apk, Bfr, out);
  hipLaunchKernelGGL(hmm_fused, dim3(NCHUNK, NBATCH / 16), dim3(640), 0, stream,
                     Apk, Bfr, inp, Iv, out);
}